// Round 12
// baseline (89.642 us; speedup 1.0000x reference)
//
#include <hip/hip_runtime.h>
#include <hip/hip_cooperative_groups.h>
#include <math.h>

namespace cg = cooperative_groups;

#define HH 30
#define WWID 30
#define HW 900
#define SENTV 900
#define DD 256
#define MAXK 16
#define AK 264      // a-buffer row stride (ushorts)
#define NFRAG 24576 // 3 matrices * 512 ntile-ktile pairs * 64 lanes... (3*8192)

typedef __attribute__((ext_vector_type(8))) short short8b;
typedef __attribute__((ext_vector_type(4))) float f32x4;

__device__ __forceinline__ float gelu_exact(float x) {
    return 0.5f * x * (1.0f + erff(x * 0.70710678118654752440f));
}

__device__ __forceinline__ unsigned short f2bf(float x) {
    unsigned int u = __float_as_uint(x);
    u += 0x7FFFu + ((u >> 16) & 1u);   // RNE
    return (unsigned short)(u >> 16);
}

// ================= MFMA pass: D(16x16 tile ntile=wv) = A(16x256) @ W ========
// (fragment layout HW-verified R8-R11)
__device__ __forceinline__ void mfma_pass16(
    const unsigned short (* __restrict__ ab)[AK],
    const unsigned short* __restrict__ wm,
    f32x4* acc, int cl, int tx, int wv)
{
    short8b afr[8];
    #pragma unroll
    for (int kt = 0; kt < 8; ++kt)
        afr[kt] = *(const short8b*)&ab[cl][kt * 32 + (tx >> 4) * 8];
    const short8b* base = (const short8b*)wm;
    short8b bfr[8];
    #pragma unroll
    for (int kt = 0; kt < 8; ++kt)
        bfr[kt] = base[(wv * 8 + kt) * 64 + tx];
    #pragma unroll
    for (int kt = 0; kt < 8; ++kt)
        *acc = __builtin_amdgcn_mfma_f32_16x16x32_bf16(afr[kt], bfr[kt], *acc, 0, 0, 0);
}

// ============ single cooperative kernel: convert + front + 3 GEMMs ===========
__global__ __launch_bounds__(1024, 4) void ccce_main(
    const float* __restrict__ grid_emb,
    const int* __restrict__ grid,
    const float* __restrict__ structure_rep,
    unsigned short* __restrict__ wsw,
    const float* __restrict__ W1, const float* __restrict__ W2,
    const float* __restrict__ Wp,
    const float* __restrict__ b1, const float* __restrict__ b2,
    const float* __restrict__ bp,
    const float* __restrict__ gvec, const float* __restrict__ bvec,
    const float* __restrict__ ortho_scale,
    float* __restrict__ out, int KS)
{
    const int b   = blockIdx.x;
    const int tid = threadIdx.x;
    const int tx  = tid & 63;
    const int wv  = tid >> 6;           // wave 0..15
    const int cl  = tx & 15;
    const int g   = tx >> 4;

    __shared__ int color_s[HW];
    __shared__ int lab_s[HW];
    __shared__ int slot_of[HW];
    __shared__ int root_s[MAXK];
    __shared__ int nroot_s;
    __shared__ int by0[MAXK], by1[MAXK], bx0[MAXK], bx1[MAXK];
    __shared__ __align__(16) unsigned short a0[16][AK];   // comb, later co
    __shared__ __align__(16) unsigned short a1[16][AK];   // hdn
    __shared__ __align__(16) float sn_s[DD];
    __shared__ float red_s[4];
    __shared__ float feats_s[16][5];
    __shared__ float dred[16][16];
    __shared__ float lred[16][16][2];

    // ---------- issue long-latency loads first ----------
    const int4* gp = (const int4*)(grid + (size_t)b * HW);
    int4 gld;
    if (tid < 225) gld = gp[tid];

    const bool do_s = (tid < DD);
    float sl0=0.f,sl1=0.f,sl2=0.f,sl3=0.f,sl4=0.f,sl5=0.f,sl6=0.f,sl7=0.f,s_gen=0.f;
    {
        const float* sr = structure_rep + (size_t)b * KS * DD + tid;
        if (do_s) {
            if (KS == 8) {
                sl0 = sr[0*DD]; sl1 = sr[1*DD]; sl2 = sr[2*DD]; sl3 = sr[3*DD];
                sl4 = sr[4*DD]; sl5 = sr[5*DD]; sl6 = sr[6*DD]; sl7 = sr[7*DD];
            } else {
                for (int j = 0; j < KS; ++j) s_gen += sr[(size_t)j * DD];
            }
        }
    }

    // ---------- distributed weight conversion (hides under the front) -------
    // Block b converts fragments [b*fpb, b*fpb+fpb); thread t does one.
    {
        const int fpb = (NFRAG + gridDim.x - 1) / gridDim.x;   // 192 for B=128
        for (int t = tid; t < fpb; t += 1024) {
            int f = b * fpb + t;
            if (f < NFRAG) {
                int m = f >> 13;
                int rem = f & 8191;
                int ntile = rem >> 9;
                int kl = rem & 511;
                int ktile = kl >> 6;
                int lane = kl & 63;
                const float* W = (m == 0) ? W1 : (m == 1) ? W2 : Wp;
                int k0 = ktile * 32 + (lane >> 4) * 8;
                int n  = ntile * 16 + (lane & 15);
                const float* src = W + (size_t)k0 * DD + n;
                float v0 = src[0*DD], v1 = src[1*DD], v2 = src[2*DD], v3 = src[3*DD];
                float v4 = src[4*DD], v5 = src[5*DD], v6 = src[6*DD], v7 = src[7*DD];
                short8b frag;
                frag[0] = (short)f2bf(v0); frag[1] = (short)f2bf(v1);
                frag[2] = (short)f2bf(v2); frag[3] = (short)f2bf(v3);
                frag[4] = (short)f2bf(v4); frag[5] = (short)f2bf(v5);
                frag[6] = (short)f2bf(v6); frag[7] = (short)f2bf(v7);
                *(short8b*)(wsw + (size_t)m * 65536 +
                            ((size_t)(ntile * 8 + ktile) * 64 + lane) * 8) = frag;
            }
        }
    }

    // ---------- grid -> LDS, init labels; init slot_of/bbox (dead time) -----
    if (tid < 225) {
        int i = tid * 4;
        color_s[i+0] = gld.x; lab_s[i+0] = (gld.x > 0) ? (i+0) : SENTV;
        color_s[i+1] = gld.y; lab_s[i+1] = (gld.y > 0) ? (i+1) : SENTV;
        color_s[i+2] = gld.z; lab_s[i+2] = (gld.z > 0) ? (i+2) : SENTV;
        color_s[i+3] = gld.w; lab_s[i+3] = (gld.w > 0) ? (i+3) : SENTV;
    }
    if (tid < HW) slot_of[tid] = -1;
    if (tid >= 1000 && tid < 1000 + MAXK) {
        int k = tid - 1000;
        by0[k] = HH; by1[k] = -1; bx0[k] = WWID; bx1[k] = -1;
    }
    __syncthreads();

    // ---------- neighbor-same-color mask (1 cell/thread) ----------
    const int li = tid;
    int nm = 0;
    if (li < HW) {
        int c = color_s[li];
        if (c > 0) {
            int r = li / WWID, cc = li - (li / WWID) * WWID;
            nm = 16;
            if (r > 0       && color_s[li - WWID] == c) nm |= 1;
            if (r < HH - 1  && color_s[li + WWID] == c) nm |= 2;
            if (cc > 0      && color_s[li - 1]    == c) nm |= 4;
            if (cc < WWID-1 && color_s[li + 1]    == c) nm |= 8;
        }
    }

    // ---------- CCL: min-label relaxation; converge-check every 2nd sweep ----
    for (;;) {
        if (nm & 16) {   // sweep 1 (no check)
            int m = lab_s[li];
            if (nm & 1) m = min(m, lab_s[li - WWID]);
            if (nm & 2) m = min(m, lab_s[li + WWID]);
            if (nm & 4) m = min(m, lab_s[li - 1]);
            if (nm & 8) m = min(m, lab_s[li + 1]);
            m = min(m, lab_s[m]);
            m = min(m, lab_s[m]);
            if (m < lab_s[li]) lab_s[li] = m;
        }
        __syncthreads();
        int ch = 0;      // sweep 2 (with check)
        if (nm & 16) {
            int m = lab_s[li];
            if (nm & 1) m = min(m, lab_s[li - WWID]);
            if (nm & 2) m = min(m, lab_s[li + WWID]);
            if (nm & 4) m = min(m, lab_s[li - 1]);
            if (nm & 8) m = min(m, lab_s[li + 1]);
            m = min(m, lab_s[m]);
            m = min(m, lab_s[m]);
            if (m < lab_s[li]) { lab_s[li] = m; ch = 1; }
        }
        if (__syncthreads_count(ch) == 0) break;
    }

    // ---------- roots + slot_of (wave 0 only; slot_of pre-inited) ----------
    if (tid < 64) {
        int base = 0;
        for (int chk = 0; chk < 15; ++chk) {
            int cell = chk * 64 + tid;
            bool isr = (cell < HW) && (color_s[cell] > 0) && (lab_s[cell] == cell);
            unsigned long long mask = __ballot(isr);
            int rank = base + __popcll(mask & ((1ull << tid) - 1ull));
            if (isr && rank < MAXK) { root_s[rank] = cell; slot_of[cell] = rank; }
            base += __popcll(mask);
        }
        if (tid == 0) nroot_s = base;
    }
    __syncthreads();

    const int nval = min(nroot_s, MAXK);

    // ---------- bbox atomics (1 cell/thread) ----------
    if (nm & 16) {
        int s = slot_of[lab_s[li]];
        if (s >= 0) {
            int r = li / WWID, cc = li - (li / WWID) * WWID;
            atomicMin(&by0[s], r); atomicMax(&by1[s], r);
            atomicMin(&bx0[s], cc); atomicMax(&bx1[s], cc);
        }
    }

    // ---------- structure mean + norm partial (waves 0-3) ----------
    float s_mean = (KS == 8)
        ? (sl0 + sl1 + sl2 + sl3 + sl4 + sl5 + sl6 + sl7) * 0.125f
        : s_gen * (1.0f / (float)KS);
    {
        float ss = s_mean * s_mean;
        #pragma unroll
        for (int off = 32; off > 0; off >>= 1) ss += __shfl_xor(ss, off);
        if (tx == 0 && wv < 4) red_s[wv] = ss;
    }
    __syncthreads();   // bboxes + red_s final

    if (do_s) {
        float nrm = sqrtf(red_s[0] + red_s[1] + red_s[2] + red_s[3]);
        sn_s[tid] = s_mean / fmaxf(nrm, 1e-8f);
    }

    // ---------- pooling: wave wv pools slot wv (8 loads in flight) ----------
    {
        const int slot = wv;
        const int v_ok = (slot < nval) ? 1 : 0;
        const int c0 = tx * 4;
        float4 pv = make_float4(0.f, 0.f, 0.f, 0.f);
        int y = 0, x = 0, h = 1, w = 1, col = 0;
        if (v_ok) {
            y = by0[slot]; x = bx0[slot];
            h = by1[slot] + 1 - y; w = bx1[slot] + 1 - x;
            col = color_s[root_s[slot]];
            const int n = h * w;   // wave-uniform
            const float* bp_ = grid_emb + ((size_t)(b * HH + y) * WWID + x) * DD + c0;
            float4 sum = make_float4(0.f, 0.f, 0.f, 0.f);
            for (int base2 = 0; base2 < n; base2 += 8) {
                float4 v[8];
                #pragma unroll
                for (int t = 0; t < 8; ++t) {
                    int ii = base2 + t;
                    if (ii < n) {
                        int yy = ii / w, xx = ii - yy * w;
                        v[t] = *(const float4*)(bp_ + ((size_t)yy * WWID + xx) * DD);
                    }
                }
                #pragma unroll
                for (int t = 0; t < 8; ++t) {
                    int ii = base2 + t;
                    if (ii < n) { sum.x += v[t].x; sum.y += v[t].y; sum.z += v[t].z; sum.w += v[t].w; }
                }
            }
            float inv = 1.0f / (float)n;
            pv.x = sum.x * inv; pv.y = sum.y * inv; pv.z = sum.z * inv; pv.w = sum.w * inv;
        }
        unsigned int p0 = (unsigned int)f2bf(pv.x) | ((unsigned int)f2bf(pv.y) << 16);
        unsigned int p1 = (unsigned int)f2bf(pv.z) | ((unsigned int)f2bf(pv.w) << 16);
        *(unsigned int*)&a0[wv][c0]     = p0;
        *(unsigned int*)&a0[wv][c0 + 2] = p1;
        if (tx < 5) {
            float f = 0.f;
            if (v_ok) {
                switch (tx) {
                    case 0: f = (float)col / 9.0f; break;
                    case 1: f = (float)x  / 30.0f; break;
                    case 2: f = (float)y  / 30.0f; break;
                    case 3: f = (float)w  / 30.0f; break;
                    case 4: f = (float)h  / 30.0f; break;
                }
            }
            feats_s[wv][tx] = f;
        }
    }
    __syncthreads();   // a0 (comb, all 16 rows) + feats + sn ready

    // ---------- grid-wide sync: all blocks' weight fragments visible --------
    __threadfence();
    cg::this_grid().sync();

    // ================= phase 1: hdn = gelu(comb @ W1 + b1) =================
    // D layout: row = g*4+j, col = wv*16+cl  (all 64 lanes active)
    {
        f32x4 acc = {0, 0, 0, 0};
        mfma_pass16(a0, wsw, &acc, cl, tx, wv);
        const int col = wv * 16 + cl;
        float b1v = b1[col];
        float tw[5];
        #pragma unroll
        for (int jj = 0; jj < 5; ++jj) tw[jj] = W1[(size_t)(256 + jj) * DD + col];
        #pragma unroll
        for (int j = 0; j < 4; ++j) {
            int row = g * 4 + j;
            float s = acc[j] + b1v;
            #pragma unroll
            for (int jj = 0; jj < 5; ++jj) s += feats_s[row][jj] * tw[jj];
            a1[row][col] = f2bf(gelu_exact(s));
        }
        __syncthreads();   // a1 (hdn) ready
    }

    // ================= phase 2: obj = (hdn@W2+b2)*valid; ortho -> co ========
    {
        f32x4 acc = {0, 0, 0, 0};
        mfma_pass16(a1, wsw + 65536, &acc, cl, tx, wv);
        const int col = wv * 16 + cl;
        float b2v = b2[col];
        float snc = sn_s[col];
        float obj[4];
        float pd[4];
        #pragma unroll
        for (int j = 0; j < 4; ++j) {
            int row = g * 4 + j;
            float vm = (row < nval) ? 1.f : 0.f;
            obj[j] = (acc[j] + b2v) * vm;
            pd[j] = obj[j] * snc;
        }
        #pragma unroll
        for (int off = 1; off < 16; off <<= 1) {
            #pragma unroll
            for (int j = 0; j < 4; ++j) pd[j] += __shfl_xor(pd[j], off);
        }
        if (cl == 0) {
            #pragma unroll
            for (int j = 0; j < 4; ++j) dred[wv][g * 4 + j] = pd[j];
        }
        __syncthreads();   // dred ready
        float osc = ortho_scale[0];
        #pragma unroll
        for (int j = 0; j < 4; ++j) {
            int row = g * 4 + j;
            float p = 0.f;
            #pragma unroll
            for (int w = 0; w < 16; ++w) p += dred[w][row];
            a0[row][col] = f2bf((obj[j] - p * snc) * osc);
        }
        __syncthreads();   // a0 (co) ready
    }

    // ================= phase 3: co @ Wp + bp, LayerNorm =====================
    {
        f32x4 acc = {0, 0, 0, 0};
        mfma_pass16(a0, wsw + 2 * 65536, &acc, cl, tx, wv);
        const int col = wv * 16 + cl;
        float bpv = bp[col];
        float v[4], S[4], Q[4];
        #pragma unroll
        for (int j = 0; j < 4; ++j) {
            v[j] = acc[j] + bpv;
            S[j] = v[j];
            Q[j] = v[j] * v[j];
        }
        #pragma unroll
        for (int off = 1; off < 16; off <<= 1) {
            #pragma unroll
            for (int j = 0; j < 4; ++j) {
                S[j] += __shfl_xor(S[j], off);
                Q[j] += __shfl_xor(Q[j], off);
            }
        }
        if (cl == 0) {
            #pragma unroll
            for (int j = 0; j < 4; ++j) {
                lred[wv][g * 4 + j][0] = S[j];
                lred[wv][g * 4 + j][1] = Q[j];
            }
        }
        __syncthreads();   // lred ready
        float gvc = gvec[col], bvc = bvec[col];
        #pragma unroll
        for (int j = 0; j < 4; ++j) {
            int row = g * 4 + j;
            float Ss = 0.f, Qq = 0.f;
            #pragma unroll
            for (int w = 0; w < 16; ++w) { Ss += lred[w][row][0]; Qq += lred[w][row][1]; }
            float mu   = Ss * (1.0f / 256.0f);
            float var  = fmaxf(Qq * (1.0f / 256.0f) - mu * mu, 0.0f);
            float rstd = 1.0f / sqrtf(var + 1e-5f);
            out[((size_t)(b * MAXK + row)) * DD + col] = (v[j] - mu) * rstd * gvc + bvc;
        }
    }
}

extern "C" void kernel_launch(void* const* d_in, const int* in_sizes, int n_in,
                              void* d_out, int out_size, void* d_ws, size_t ws_size,
                              hipStream_t stream) {
    const float* grid_emb = (const float*)d_in[0];
    const int*   grid     = (const int*)d_in[1];
    const float* srep     = (const float*)d_in[2];
    const float* W1v = (const float*)d_in[3];
    const float* b1v = (const float*)d_in[4];
    const float* W2v = (const float*)d_in[5];
    const float* b2v = (const float*)d_in[6];
    const float* Wpv = (const float*)d_in[7];
    const float* bpv = (const float*)d_in[8];
    const float* gv  = (const float*)d_in[9];
    const float* bv  = (const float*)d_in[10];
    const float* osv = (const float*)d_in[11];
    float* out = (float*)d_out;

    int B  = in_sizes[1] / HW;
    int KS = in_sizes[2] / (B * DD);
    unsigned short* wsw = (unsigned short*)d_ws;   // 384 KB used

    void* args[] = { (void*)&grid_emb, (void*)&grid, (void*)&srep, (void*)&wsw,
                     (void*)&W1v, (void*)&W2v, (void*)&Wpv,
                     (void*)&b1v, (void*)&b2v, (void*)&bpv,
                     (void*)&gv, (void*)&bv, (void*)&osv,
                     (void*)&out, (void*)&KS };
    hipLaunchCooperativeKernel((void*)ccce_main, dim3(B), dim3(1024),
                               args, 0, stream);
}

// Round 13
// 26.923 us; speedup vs baseline: 3.3296x; 3.3296x over previous
//
#include <hip/hip_runtime.h>
#include <math.h>

#define HH 30
#define WWID 30
#define HW 900
#define SENTV 900
#define DD 256
#define MAXK 16
#define AK 264   // a-buffer row stride (ushorts)

typedef __attribute__((ext_vector_type(8))) short short8b;
typedef __attribute__((ext_vector_type(4))) float f32x4;
typedef __attribute__((ext_vector_type(4))) unsigned int uint4v;

__device__ __forceinline__ float gelu_exact(float x) {
    return 0.5f * x * (1.0f + erff(x * 0.70710678118654752440f));
}

__device__ __forceinline__ unsigned short f2bf(float x) {
    unsigned int u = __float_as_uint(x);
    u += 0x7FFFu + ((u >> 16) & 1u);   // RNE
    return (unsigned short)(u >> 16);
}

__device__ __forceinline__ unsigned int cvt_pk_bf16(float a, float b) {
    unsigned int d;
    asm("v_cvt_pk_bf16_f32 %0, %1, %2" : "=v"(d) : "v"(a), "v"(b));
    return d;   // lo = bf16(a), hi = bf16(b)
}

// Load one matrix's MFMA B-fragments for (wv, cl, g) into 8 packed short8b regs.
// wf[kt] elem i = bf16(W[kt*32 + g*8 + i][wv*16 + cl])  — layout HW-verified R8-R11.
// Two 32-load bursts keep transient f32 regs at 32.
__device__ __forceinline__ void load_wfrags(
    const float* __restrict__ W, int wv, int cl, int g, short8b wf[8])
{
    const float* src = W + (size_t)(g * 8) * DD + (wv * 16 + cl);
    #pragma unroll
    for (int half = 0; half < 2; ++half) {
        float v[4][8];
        #pragma unroll
        for (int kt = 0; kt < 4; ++kt) {
            #pragma unroll
            for (int i = 0; i < 8; ++i)
                v[kt][i] = src[(size_t)((half * 4 + kt) * 32 + i) * DD];
        }
        #pragma unroll
        for (int kt = 0; kt < 4; ++kt) {
            union { uint4v u; short8b s; } cv;
            cv.u[0] = cvt_pk_bf16(v[kt][0], v[kt][1]);
            cv.u[1] = cvt_pk_bf16(v[kt][2], v[kt][3]);
            cv.u[2] = cvt_pk_bf16(v[kt][4], v[kt][5]);
            cv.u[3] = cvt_pk_bf16(v[kt][6], v[kt][7]);
            wf[half * 4 + kt] = cv.s;
        }
    }
}

// MFMA pass: D(16x16 tile ntile=wv) = A(16x256 in LDS) @ W(regs)
__device__ __forceinline__ void mfma_pass_reg(
    const unsigned short (* __restrict__ ab)[AK],
    const short8b wf[8], f32x4* acc, int cl, int g)
{
    short8b afr[8];
    #pragma unroll
    for (int kt = 0; kt < 8; ++kt)
        afr[kt] = *(const short8b*)&ab[cl][kt * 32 + g * 8];
    #pragma unroll
    for (int kt = 0; kt < 8; ++kt)
        *acc = __builtin_amdgcn_mfma_f32_16x16x32_bf16(afr[kt], wf[kt], *acc, 0, 0, 0);
}

// ======== single kernel: front + in-register weight convert + 3 GEMMs ========
__global__ __launch_bounds__(1024, 4) void ccce_main(
    const float* __restrict__ grid_emb,
    const int* __restrict__ grid,
    const float* __restrict__ structure_rep,
    const float* __restrict__ W1, const float* __restrict__ W2,
    const float* __restrict__ Wp,
    const float* __restrict__ b1, const float* __restrict__ b2,
    const float* __restrict__ bp,
    const float* __restrict__ gvec, const float* __restrict__ bvec,
    const float* __restrict__ ortho_scale,
    float* __restrict__ out, int KS)
{
    const int b   = blockIdx.x;
    const int tid = threadIdx.x;
    const int tx  = tid & 63;
    const int wv  = tid >> 6;           // wave 0..15
    const int cl  = tx & 15;
    const int g   = tx >> 4;

    __shared__ int color_s[HW];
    __shared__ int lab_s[HW];
    __shared__ int slot_of[HW];
    __shared__ int root_s[MAXK];
    __shared__ int nroot_s;
    __shared__ int by0[MAXK], by1[MAXK], bx0[MAXK], bx1[MAXK];
    __shared__ __align__(16) unsigned short a0[16][AK];   // comb, later co
    __shared__ __align__(16) unsigned short a1[16][AK];   // hdn
    __shared__ __align__(16) float sn_s[DD];
    __shared__ float red_s[4];
    __shared__ float feats_s[16][5];
    __shared__ float dred[16][16];
    __shared__ float lred[16][16][2];

    // ---------- issue long-latency loads first ----------
    const int4* gp = (const int4*)(grid + (size_t)b * HW);
    int4 gld;
    if (tid < 225) gld = gp[tid];

    const bool do_s = (tid < DD);
    float sl0=0.f,sl1=0.f,sl2=0.f,sl3=0.f,sl4=0.f,sl5=0.f,sl6=0.f,sl7=0.f,s_gen=0.f;
    {
        const float* sr = structure_rep + (size_t)b * KS * DD + tid;
        if (do_s) {
            if (KS == 8) {
                sl0 = sr[0*DD]; sl1 = sr[1*DD]; sl2 = sr[2*DD]; sl3 = sr[3*DD];
                sl4 = sr[4*DD]; sl5 = sr[5*DD]; sl6 = sr[6*DD]; sl7 = sr[7*DD];
            } else {
                for (int j = 0; j < KS; ++j) s_gen += sr[(size_t)j * DD];
            }
        }
    }

    // ---------- grid -> LDS, init labels; slot_of/bbox init (dead time) -----
    if (tid < 225) {
        int i = tid * 4;
        color_s[i+0] = gld.x; lab_s[i+0] = (gld.x > 0) ? (i+0) : SENTV;
        color_s[i+1] = gld.y; lab_s[i+1] = (gld.y > 0) ? (i+1) : SENTV;
        color_s[i+2] = gld.z; lab_s[i+2] = (gld.z > 0) ? (i+2) : SENTV;
        color_s[i+3] = gld.w; lab_s[i+3] = (gld.w > 0) ? (i+3) : SENTV;
    }
    if (tid < HW) slot_of[tid] = -1;
    if (tid >= 1000 && tid < 1000 + MAXK) {
        int k = tid - 1000;
        by0[k] = HH; by1[k] = -1; bx0[k] = WWID; bx1[k] = -1;
    }
    __syncthreads();

    // ---------- neighbor-same-color mask (1 cell/thread) ----------
    const int li = tid;
    int nm = 0;
    if (li < HW) {
        int c = color_s[li];
        if (c > 0) {
            int r = li / WWID, cc = li - (li / WWID) * WWID;
            nm = 16;
            if (r > 0       && color_s[li - WWID] == c) nm |= 1;
            if (r < HH - 1  && color_s[li + WWID] == c) nm |= 2;
            if (cc > 0      && color_s[li - 1]    == c) nm |= 4;
            if (cc < WWID-1 && color_s[li + 1]    == c) nm |= 8;
        }
    }

    // ---------- W1 fragments -> regs (latency hides under CCL) ----------
    short8b wfA[8];
    load_wfrags(W1, wv, cl, g, wfA);

    // ---------- CCL: min-label relaxation; converge-check every 2nd sweep ----
    for (;;) {
        if (nm & 16) {   // sweep 1 (no check)
            int m = lab_s[li];
            if (nm & 1) m = min(m, lab_s[li - WWID]);
            if (nm & 2) m = min(m, lab_s[li + WWID]);
            if (nm & 4) m = min(m, lab_s[li - 1]);
            if (nm & 8) m = min(m, lab_s[li + 1]);
            m = min(m, lab_s[m]);
            m = min(m, lab_s[m]);
            if (m < lab_s[li]) lab_s[li] = m;
        }
        __syncthreads();
        int ch = 0;      // sweep 2 (with check)
        if (nm & 16) {
            int m = lab_s[li];
            if (nm & 1) m = min(m, lab_s[li - WWID]);
            if (nm & 2) m = min(m, lab_s[li + WWID]);
            if (nm & 4) m = min(m, lab_s[li - 1]);
            if (nm & 8) m = min(m, lab_s[li + 1]);
            m = min(m, lab_s[m]);
            m = min(m, lab_s[m]);
            if (m < lab_s[li]) { lab_s[li] = m; ch = 1; }
        }
        if (__syncthreads_count(ch) == 0) break;
    }

    // ---------- roots + slot_of (wave 0; slot_of pre-inited) ----------
    if (tid < 64) {
        int base = 0;
        for (int chk = 0; chk < 15; ++chk) {
            int cell = chk * 64 + tid;
            bool isr = (cell < HW) && (color_s[cell] > 0) && (lab_s[cell] == cell);
            unsigned long long mask = __ballot(isr);
            int rank = base + __popcll(mask & ((1ull << tid) - 1ull));
            if (isr && rank < MAXK) { root_s[rank] = cell; slot_of[cell] = rank; }
            base += __popcll(mask);
        }
        if (tid == 0) nroot_s = base;
    }
    __syncthreads();

    const int nval = min(nroot_s, MAXK);

    // ---------- bbox atomics (1 cell/thread) ----------
    if (nm & 16) {
        int s = slot_of[lab_s[li]];
        if (s >= 0) {
            int r = li / WWID, cc = li - (li / WWID) * WWID;
            atomicMin(&by0[s], r); atomicMax(&by1[s], r);
            atomicMin(&bx0[s], cc); atomicMax(&bx1[s], cc);
        }
    }

    // ---------- structure mean + norm partial ----------
    float s_mean = (KS == 8)
        ? (sl0 + sl1 + sl2 + sl3 + sl4 + sl5 + sl6 + sl7) * 0.125f
        : s_gen * (1.0f / (float)KS);
    {
        float ss = s_mean * s_mean;
        #pragma unroll
        for (int off = 32; off > 0; off >>= 1) ss += __shfl_xor(ss, off);
        if (tx == 0 && wv < 4) red_s[wv] = ss;
    }
    __syncthreads();   // bboxes + red_s final

    if (do_s) {
        float nrm = sqrtf(red_s[0] + red_s[1] + red_s[2] + red_s[3]);
        sn_s[tid] = s_mean / fmaxf(nrm, 1e-8f);
    }

    // ---------- pooling: wave wv pools slot wv (8 loads in flight) ----------
    {
        const int slot = wv;
        const int v_ok = (slot < nval) ? 1 : 0;
        const int c0 = tx * 4;
        float4 pv = make_float4(0.f, 0.f, 0.f, 0.f);
        int y = 0, x = 0, h = 1, w = 1, col = 0;
        if (v_ok) {
            y = by0[slot]; x = bx0[slot];
            h = by1[slot] + 1 - y; w = bx1[slot] + 1 - x;
            col = color_s[root_s[slot]];
            const int n = h * w;   // wave-uniform
            const float* bp_ = grid_emb + ((size_t)(b * HH + y) * WWID + x) * DD + c0;
            float4 sum = make_float4(0.f, 0.f, 0.f, 0.f);
            for (int base2 = 0; base2 < n; base2 += 8) {
                float4 v[8];
                #pragma unroll
                for (int t = 0; t < 8; ++t) {
                    int ii = base2 + t;
                    if (ii < n) {
                        int yy = ii / w, xx = ii - yy * w;
                        v[t] = *(const float4*)(bp_ + ((size_t)yy * WWID + xx) * DD);
                    }
                }
                #pragma unroll
                for (int t = 0; t < 8; ++t) {
                    int ii = base2 + t;
                    if (ii < n) { sum.x += v[t].x; sum.y += v[t].y; sum.z += v[t].z; sum.w += v[t].w; }
                }
            }
            float inv = 1.0f / (float)n;
            pv.x = sum.x * inv; pv.y = sum.y * inv; pv.z = sum.z * inv; pv.w = sum.w * inv;
        }
        unsigned int p0 = (unsigned int)f2bf(pv.x) | ((unsigned int)f2bf(pv.y) << 16);
        unsigned int p1 = (unsigned int)f2bf(pv.z) | ((unsigned int)f2bf(pv.w) << 16);
        *(unsigned int*)&a0[wv][c0]     = p0;
        *(unsigned int*)&a0[wv][c0 + 2] = p1;
        if (tx < 5) {
            float f = 0.f;
            if (v_ok) {
                switch (tx) {
                    case 0: f = (float)col / 9.0f; break;
                    case 1: f = (float)x  / 30.0f; break;
                    case 2: f = (float)y  / 30.0f; break;
                    case 3: f = (float)w  / 30.0f; break;
                    case 4: f = (float)h  / 30.0f; break;
                }
            }
            feats_s[wv][tx] = f;
        }
    }

    // ---------- W2 fragments -> regs (latency hides under phase 1) ----------
    short8b wfB[8];
    load_wfrags(W2, wv, cl, g, wfB);
    __syncthreads();   // a0 (comb, 16 rows) + feats + sn ready

    // ================= phase 1: hdn = gelu(comb @ W1 + b1) =================
    // D layout: row = g*4+j, col = wv*16+cl  (all 64 lanes active)
    {
        f32x4 acc = {0, 0, 0, 0};
        mfma_pass_reg(a0, wfA, &acc, cl, g);
        const int col = wv * 16 + cl;
        float b1v = b1[col];
        float tw[5];
        #pragma unroll
        for (int jj = 0; jj < 5; ++jj) tw[jj] = W1[(size_t)(256 + jj) * DD + col];
        #pragma unroll
        for (int j = 0; j < 4; ++j) {
            int row = g * 4 + j;
            float s = acc[j] + b1v;
            #pragma unroll
            for (int jj = 0; jj < 5; ++jj) s += feats_s[row][jj] * tw[jj];
            a1[row][col] = f2bf(gelu_exact(s));
        }
        __syncthreads();   // a1 (hdn) ready
    }

    // ================= phase 2: obj = (hdn@W2+b2)*valid; ortho -> co ========
    short8b wfC[8];
    {
        f32x4 acc = {0, 0, 0, 0};
        mfma_pass_reg(a1, wfB, &acc, cl, g);
        load_wfrags(Wp, wv, cl, g, wfC);   // hidden under epilogue + barriers
        const int col = wv * 16 + cl;
        float b2v = b2[col];
        float snc = sn_s[col];
        float obj[4];
        float pd[4];
        #pragma unroll
        for (int j = 0; j < 4; ++j) {
            int row = g * 4 + j;
            float vm = (row < nval) ? 1.f : 0.f;
            obj[j] = (acc[j] + b2v) * vm;
            pd[j] = obj[j] * snc;
        }
        #pragma unroll
        for (int off = 1; off < 16; off <<= 1) {
            #pragma unroll
            for (int j = 0; j < 4; ++j) pd[j] += __shfl_xor(pd[j], off);
        }
        if (cl == 0) {
            #pragma unroll
            for (int j = 0; j < 4; ++j) dred[wv][g * 4 + j] = pd[j];
        }
        __syncthreads();   // dred ready
        float osc = ortho_scale[0];
        #pragma unroll
        for (int j = 0; j < 4; ++j) {
            int row = g * 4 + j;
            float p = 0.f;
            #pragma unroll
            for (int w = 0; w < 16; ++w) p += dred[w][row];
            a0[row][col] = f2bf((obj[j] - p * snc) * osc);
        }
        __syncthreads();   // a0 (co) ready
    }

    // ================= phase 3: co @ Wp + bp, LayerNorm =====================
    {
        f32x4 acc = {0, 0, 0, 0};
        mfma_pass_reg(a0, wfC, &acc, cl, g);
        const int col = wv * 16 + cl;
        float bpv = bp[col];
        float v[4], S[4], Q[4];
        #pragma unroll
        for (int j = 0; j < 4; ++j) {
            v[j] = acc[j] + bpv;
            S[j] = v[j];
            Q[j] = v[j] * v[j];
        }
        #pragma unroll
        for (int off = 1; off < 16; off <<= 1) {
            #pragma unroll
            for (int j = 0; j < 4; ++j) {
                S[j] += __shfl_xor(S[j], off);
                Q[j] += __shfl_xor(Q[j], off);
            }
        }
        if (cl == 0) {
            #pragma unroll
            for (int j = 0; j < 4; ++j) {
                lred[wv][g * 4 + j][0] = S[j];
                lred[wv][g * 4 + j][1] = Q[j];
            }
        }
        __syncthreads();   // lred ready
        float gvc = gvec[col], bvc = bvec[col];
        #pragma unroll
        for (int j = 0; j < 4; ++j) {
            int row = g * 4 + j;
            float Ss = 0.f, Qq = 0.f;
            #pragma unroll
            for (int w = 0; w < 16; ++w) { Ss += lred[w][row][0]; Qq += lred[w][row][1]; }
            float mu   = Ss * (1.0f / 256.0f);
            float var  = fmaxf(Qq * (1.0f / 256.0f) - mu * mu, 0.0f);
            float rstd = 1.0f / sqrtf(var + 1e-5f);
            out[((size_t)(b * MAXK + row)) * DD + col] = (v[j] - mu) * rstd * gvc + bvc;
        }
    }
}

extern "C" void kernel_launch(void* const* d_in, const int* in_sizes, int n_in,
                              void* d_out, int out_size, void* d_ws, size_t ws_size,
                              hipStream_t stream) {
    const float* grid_emb = (const float*)d_in[0];
    const int*   grid     = (const int*)d_in[1];
    const float* srep     = (const float*)d_in[2];
    const float* W1v = (const float*)d_in[3];
    const float* b1v = (const float*)d_in[4];
    const float* W2v = (const float*)d_in[5];
    const float* b2v = (const float*)d_in[6];
    const float* Wpv = (const float*)d_in[7];
    const float* bpv = (const float*)d_in[8];
    const float* gv  = (const float*)d_in[9];
    const float* bv  = (const float*)d_in[10];
    const float* osv = (const float*)d_in[11];
    float* out = (float*)d_out;

    const int B  = in_sizes[1] / HW;
    const int KS = in_sizes[2] / (B * DD);

    hipLaunchKernelGGL(ccce_main, dim3(B), dim3(1024), 0, stream,
                       grid_emb, grid, srep, W1v, W2v, Wpv,
                       b1v, b2v, bpv, gv, bv, osv, out, KS);
}